// Round 1
// baseline (1725.898 us; speedup 1.0000x reference)
//
#include <hip/hip_runtime.h>
#include <math.h>

#define BATCH 8
#define SEQ 2048
#define DIM 512
#define MTOT (BATCH*SEQ)
#define HID 30

// ---------------- K0a: G[q1][q2] = sum_d Wq[d][q1] * Wk[d][q2] ----------------
__global__ __launch_bounds__(256) void k_gmat(const float* __restrict__ Wq,
                                              const float* __restrict__ Wk,
                                              float* __restrict__ G) {
  __shared__ __align__(16) float As[16][68];
  __shared__ __align__(16) float Bs[16][68];
  int t = threadIdx.x;
  int tm = t & 15, tn = t >> 4;
  int q1b = blockIdx.x * 64, q2b = blockIdx.y * 64;
  int lk = t >> 4, lc = (t & 15) * 4;
  float acc[4][4] = {};
  for (int kb = 0; kb < DIM; kb += 16) {
    *(float4*)&As[lk][lc] = *(const float4*)&Wq[(size_t)(kb + lk) * DIM + q1b + lc];
    *(float4*)&Bs[lk][lc] = *(const float4*)&Wk[(size_t)(kb + lk) * DIM + q2b + lc];
    __syncthreads();
#pragma unroll
    for (int k = 0; k < 16; ++k) {
      float4 av = *(float4*)&As[k][tm * 4];
      float4 bv = *(float4*)&Bs[k][tn * 4];
      float a[4] = {av.x, av.y, av.z, av.w};
      float b[4] = {bv.x, bv.y, bv.z, bv.w};
#pragma unroll
      for (int i = 0; i < 4; ++i)
#pragma unroll
        for (int j = 0; j < 4; ++j) acc[i][j] = fmaf(a[i], b[j], acc[i][j]);
    }
    __syncthreads();
  }
#pragma unroll
  for (int i = 0; i < 4; ++i) {
    float4 v = make_float4(acc[i][0], acc[i][1], acc[i][2], acc[i][3]);
    *(float4*)&G[(size_t)(q1b + tm * 4 + i) * DIM + q2b + tn * 4] = v;
  }
}

// ---------------- K0b: u[q]=sum_d bq[d]Wk[d][q]; w[q]=sum_d Wq[d][q]bk[d]; s0=bq.bk --------
__global__ void k_small(const float* __restrict__ bq, const float* __restrict__ Wk,
                        const float* __restrict__ Wq, const float* __restrict__ bk,
                        float* __restrict__ u, float* __restrict__ w, float* __restrict__ s0) {
  int t = threadIdx.x;
  if (blockIdx.x == 0) {
    float s = 0.f;
    for (int d = 0; d < DIM; ++d) s = fmaf(bq[d], Wk[(size_t)d * DIM + t], s);
    u[t] = s;
  } else if (blockIdx.x == 1) {
    float s = 0.f;
    for (int d = 0; d < DIM; ++d) s = fmaf(Wq[(size_t)d * DIM + t], bk[d], s);
    w[t] = s;
  } else {
    __shared__ float red[512];
    red[t] = bq[t] * bk[t];
    __syncthreads();
    for (int o = 256; o > 0; o >>= 1) {
      if (t < o) red[t] += red[t + o];
      __syncthreads();
    }
    if (t == 0) *s0 = red[0];
  }
}

// ---------------- K1b: c[n] = R[n].w + s0 ----------------
__global__ __launch_bounds__(256) void k_cvec(const float* __restrict__ R,
                                              const float* __restrict__ w,
                                              const float* __restrict__ s0,
                                              float* __restrict__ c) {
  int wave = threadIdx.x >> 6, lane = threadIdx.x & 63;
  int n = blockIdx.x * 4 + wave;
  const float* p = &R[(size_t)n * DIM + lane * 8];
  float4 r0 = *(const float4*)p;
  float4 r1 = *(const float4*)(p + 4);
  float4 w0 = *(const float4*)&w[lane * 8];
  float4 w1 = *(const float4*)&w[lane * 8 + 4];
  float s = r0.x * w0.x + r0.y * w0.y + r0.z * w0.z + r0.w * w0.w +
            r1.x * w1.x + r1.y * w1.y + r1.z * w1.z + r1.w * w1.w;
#pragma unroll
  for (int o = 32; o > 0; o >>= 1) s += __shfl_down(s, o);
  if (lane == 0) c[n] = s + s0[0];
}

// ---------------- K1: T = R@G + u  (z=0)  /  V = R@Wv^T + bv  (z=1) ----------------
__global__ __launch_bounds__(256) void k_proj(const float* __restrict__ R,
                                              const float* __restrict__ Gm,
                                              const float* __restrict__ u,
                                              const float* __restrict__ Wv,
                                              const float* __restrict__ bv,
                                              float* __restrict__ T,
                                              float* __restrict__ V) {
  __shared__ __align__(16) float As[16][132];
  __shared__ __align__(16) float Bs[16][132];
  int t = threadIdx.x;
  int tm = t & 15, tn = t >> 4;
  int rowb = blockIdx.x * 128;
  int colb = blockIdx.y * 128;
  bool isV = (blockIdx.z != 0);
  int ar = t >> 1, ak = (t & 1) * 8;   // A staging: 128 rows x 16 k
  int gk = t >> 4, gc = (t & 15) * 8;  // B staging (G): 16 k x 128 c
  float acc[2][2][4][4] = {};
  for (int kb = 0; kb < DIM; kb += 16) {
    {
      const float* p = &R[(size_t)(rowb + ar) * DIM + kb + ak];
      float4 a0 = *(const float4*)p;
      float4 a1 = *(const float4*)(p + 4);
      As[ak + 0][ar] = a0.x; As[ak + 1][ar] = a0.y; As[ak + 2][ar] = a0.z; As[ak + 3][ar] = a0.w;
      As[ak + 4][ar] = a1.x; As[ak + 5][ar] = a1.y; As[ak + 6][ar] = a1.z; As[ak + 7][ar] = a1.w;
    }
    if (!isV) {
      const float* p = &Gm[(size_t)(kb + gk) * DIM + colb + gc];
      *(float4*)&Bs[gk][gc] = *(const float4*)p;
      *(float4*)&Bs[gk][gc + 4] = *(const float4*)(p + 4);
    } else {
      const float* p = &Wv[(size_t)(colb + ar) * DIM + kb + ak];
      float4 b0 = *(const float4*)p;
      float4 b1 = *(const float4*)(p + 4);
      Bs[ak + 0][ar] = b0.x; Bs[ak + 1][ar] = b0.y; Bs[ak + 2][ar] = b0.z; Bs[ak + 3][ar] = b0.w;
      Bs[ak + 4][ar] = b1.x; Bs[ak + 5][ar] = b1.y; Bs[ak + 6][ar] = b1.z; Bs[ak + 7][ar] = b1.w;
    }
    __syncthreads();
#pragma unroll
    for (int k = 0; k < 16; ++k) {
      float4 a0v = *(float4*)&As[k][tm * 4];
      float4 a1v = *(float4*)&As[k][64 + tm * 4];
      float4 b0v = *(float4*)&Bs[k][tn * 4];
      float4 b1v = *(float4*)&Bs[k][64 + tn * 4];
      float a[2][4] = {{a0v.x, a0v.y, a0v.z, a0v.w}, {a1v.x, a1v.y, a1v.z, a1v.w}};
      float b[2][4] = {{b0v.x, b0v.y, b0v.z, b0v.w}, {b1v.x, b1v.y, b1v.z, b1v.w}};
#pragma unroll
      for (int ri = 0; ri < 2; ++ri)
#pragma unroll
        for (int ci = 0; ci < 2; ++ci)
#pragma unroll
          for (int i = 0; i < 4; ++i)
#pragma unroll
            for (int j = 0; j < 4; ++j)
              acc[ri][ci][i][j] = fmaf(a[ri][i], b[ci][j], acc[ri][ci][i][j]);
    }
    __syncthreads();
  }
  const float* bias = isV ? bv : u;
  float* out = isV ? V : T;
#pragma unroll
  for (int ci = 0; ci < 2; ++ci) {
    float bb[4];
#pragma unroll
    for (int j = 0; j < 4; ++j) bb[j] = bias[colb + ci * 64 + tn * 4 + j];
#pragma unroll
    for (int ri = 0; ri < 2; ++ri)
#pragma unroll
      for (int i = 0; i < 4; ++i) {
        float4 v = make_float4(acc[ri][ci][i][0] + bb[0], acc[ri][ci][i][1] + bb[1],
                               acc[ri][ci][i][2] + bb[2], acc[ri][ci][i][3] + bb[3]);
        *(float4*)&out[(size_t)(rowb + ri * 64 + tm * 4 + i) * DIM + colb + ci * 64 + tn * 4] = v;
      }
  }
}

// ---------------- K2: flash attention (no-rescale exp) + fused fc head ----------------
// qblock = 32 rows, m-tile = 64. gamma[n,m] = (T[n].R[m] + c[n]) / sqrt(512)
__global__ __launch_bounds__(256) void k_attn(const float* __restrict__ T,
                                              const float* __restrict__ R,
                                              const float* __restrict__ V,
                                              const float* __restrict__ cvec,
                                              const float* __restrict__ W1,
                                              const float* __restrict__ b1,
                                              const float* __restrict__ W2,
                                              const float* __restrict__ b2,
                                              float* __restrict__ out) {
  __shared__ __align__(16) float uarea[4352];  // union: {As[32][34]+Bs[32][68]} | Vs[64][68] | {a_s[32][65]+W1T[64][32]}
  __shared__ float eT[64][34];
  __shared__ float c_s[32];
  __shared__ float outp[4][32];
  float (*As)[34]  = (float(*)[34])uarea;
  float (*Bs)[68]  = (float(*)[68])(uarea + 32 * 34);
  float (*Vs)[68]  = (float(*)[68])uarea;
  float (*a_s)[65] = (float(*)[65])uarea;
  float (*W1T)[32] = (float(*)[32])(uarea + 32 * 65);

  int t = threadIdx.x;
  int b = blockIdx.y;
  int nb = blockIdx.x * 32;
  const float* Tb = T + ((size_t)b * SEQ + nb) * DIM;
  const float* Rb = R + (size_t)b * SEQ * DIM;
  const float* Vb = V + (size_t)b * SEQ * DIM;
  int tr = t >> 4, tc = t & 15;
  if (t < 32) c_s[t] = cvec[b * SEQ + nb + t];
  float num[8][2][4] = {};
  float den[2] = {0.f, 0.f};
  const float rs = 0.044194173824159216f;  // 1/sqrt(512)
  int sar = t >> 3, sak = (t & 7) * 4;  // As staging (T): 32r x 32k
  int sbm = t >> 2, sbk = (t & 3) * 8;  // Bs staging (R): 64m x 32k
  int svm = t >> 2, svd = (t & 3) * 16; // Vs staging:     64m x 64d

  for (int mb = 0; mb < SEQ; mb += 64) {
    float S[2][4] = {};
    for (int kb = 0; kb < DIM; kb += 32) {
      {
        float4 v = *(const float4*)&Tb[(size_t)sar * DIM + kb + sak];
        As[sak + 0][sar] = v.x; As[sak + 1][sar] = v.y; As[sak + 2][sar] = v.z; As[sak + 3][sar] = v.w;
      }
      {
        const float* p = &Rb[(size_t)(mb + sbm) * DIM + kb + sbk];
        float4 v0 = *(const float4*)p;
        float4 v1 = *(const float4*)(p + 4);
        Bs[sbk + 0][sbm] = v0.x; Bs[sbk + 1][sbm] = v0.y; Bs[sbk + 2][sbm] = v0.z; Bs[sbk + 3][sbm] = v0.w;
        Bs[sbk + 4][sbm] = v1.x; Bs[sbk + 5][sbm] = v1.y; Bs[sbk + 6][sbm] = v1.z; Bs[sbk + 7][sbm] = v1.w;
      }
      __syncthreads();
#pragma unroll
      for (int k = 0; k < 32; ++k) {
        float a0 = As[k][tr * 2], a1 = As[k][tr * 2 + 1];
        float4 bv4 = *(float4*)&Bs[k][tc * 4];
        float bb[4] = {bv4.x, bv4.y, bv4.z, bv4.w};
#pragma unroll
        for (int j = 0; j < 4; ++j) {
          S[0][j] = fmaf(a0, bb[j], S[0][j]);
          S[1][j] = fmaf(a1, bb[j], S[1][j]);
        }
      }
      __syncthreads();
    }
    // e = exp(gamma); accumulate denominator; stash e transposed for PV
#pragma unroll
    for (int i = 0; i < 2; ++i) {
      float cv = c_s[tr * 2 + i];
#pragma unroll
      for (int j = 0; j < 4; ++j) {
        float e = __expf((S[i][j] + cv) * rs);
        den[i] += e;
        eT[tc * 4 + j][tr * 2 + i] = e;
      }
    }
    // PV: num[r][d] += e[r][m] * V[m][d], d in 8 chunks of 64
#pragma unroll
    for (int ci = 0; ci < 8; ++ci) {
      {
        const float* p = &Vb[(size_t)(mb + svm) * DIM + ci * 64 + svd];
        *(float4*)&Vs[svm][svd]      = *(const float4*)p;
        *(float4*)&Vs[svm][svd + 4]  = *(const float4*)(p + 4);
        *(float4*)&Vs[svm][svd + 8]  = *(const float4*)(p + 8);
        *(float4*)&Vs[svm][svd + 12] = *(const float4*)(p + 12);
      }
      __syncthreads();
#pragma unroll 16
      for (int mm = 0; mm < 64; ++mm) {
        float e0 = eT[mm][tr * 2], e1 = eT[mm][tr * 2 + 1];
        float4 vv4 = *(float4*)&Vs[mm][tc * 4];
        float vv[4] = {vv4.x, vv4.y, vv4.z, vv4.w};
#pragma unroll
        for (int j = 0; j < 4; ++j) {
          num[ci][0][j] = fmaf(e0, vv[j], num[ci][0][j]);
          num[ci][1][j] = fmaf(e1, vv[j], num[ci][1][j]);
        }
      }
      __syncthreads();
    }
  }
  // deterministic denominator reduce across the 16 tc lanes (same wave)
#pragma unroll
  for (int i = 0; i < 2; ++i) {
#pragma unroll
    for (int m = 1; m < 16; m <<= 1) den[i] += __shfl_xor(den[i], m);
  }
  float rden[2] = {1.f / den[0], 1.f / den[1]};

  // fused head: h = a@W1^T + b1 ; out = h.W2 + b2
  int r_h = t & 31, grp = t >> 5;  // 8 groups x 4 j-slots (j>=30 padded)
  float h[4];
#pragma unroll
  for (int jj = 0; jj < 4; ++jj) {
    int j = grp * 4 + jj;
    h[jj] = (j < HID) ? b1[j] : 0.f;
  }
#pragma unroll
  for (int ci = 0; ci < 8; ++ci) {
    __syncthreads();  // previous chunk reads done before overwriting a_s/W1T
#pragma unroll
    for (int i = 0; i < 2; ++i)
#pragma unroll
      for (int j = 0; j < 4; ++j)
        a_s[tr * 2 + i][tc * 4 + j] = num[ci][i][j] * rden[i];
    {
      int js = t >> 3, cc0 = (t & 7) * 8;
      if (js < HID) {
        const float* p = &W1[(size_t)js * DIM + ci * 64 + cc0];
        float4 w0 = *(const float4*)p;
        float4 w1 = *(const float4*)(p + 4);
        W1T[cc0 + 0][js] = w0.x; W1T[cc0 + 1][js] = w0.y; W1T[cc0 + 2][js] = w0.z; W1T[cc0 + 3][js] = w0.w;
        W1T[cc0 + 4][js] = w1.x; W1T[cc0 + 5][js] = w1.y; W1T[cc0 + 6][js] = w1.z; W1T[cc0 + 7][js] = w1.w;
      } else {
#pragma unroll
        for (int i = 0; i < 8; ++i) W1T[cc0 + i][js] = 0.f;
      }
    }
    __syncthreads();
#pragma unroll 8
    for (int cc = 0; cc < 64; ++cc) {
      float va = a_s[r_h][cc];
      float4 wv4 = *(float4*)&W1T[cc][grp * 4];
      float wv[4] = {wv4.x, wv4.y, wv4.z, wv4.w};
#pragma unroll
      for (int jj = 0; jj < 4; ++jj) h[jj] = fmaf(va, wv[jj], h[jj]);
    }
  }
  float po = 0.f;
#pragma unroll
  for (int jj = 0; jj < 4; ++jj) {
    int j = grp * 4 + jj;
    if (j < HID) po = fmaf(h[jj], W2[j], po);
  }
  po += __shfl_xor(po, 32);  // combine the 2 groups within each wave
  if ((t & 63) < 32) outp[t >> 6][t & 31] = po;
  __syncthreads();
  if (t < 32)
    out[(size_t)b * SEQ + nb + t] = outp[0][t] + outp[1][t] + outp[2][t] + outp[3][t] + b2[0];
}

extern "C" void kernel_launch(void* const* d_in, const int* in_sizes, int n_in,
                              void* d_out, int out_size, void* d_ws, size_t ws_size,
                              hipStream_t stream) {
  const float* R  = (const float*)d_in[0];
  const float* Wq = (const float*)d_in[1];
  const float* bq = (const float*)d_in[2];
  const float* Wk = (const float*)d_in[3];
  const float* bk = (const float*)d_in[4];
  const float* Wv = (const float*)d_in[5];
  const float* bv = (const float*)d_in[6];
  const float* W1 = (const float*)d_in[7];
  const float* b1 = (const float*)d_in[8];
  const float* W2 = (const float*)d_in[9];
  const float* b2 = (const float*)d_in[10];
  float* ws = (float*)d_ws;
  // ws layout (floats): T[16384*512], V[16384*512], G[512*512], u[512], w[512], s0[1], c[16384]
  float* T  = ws;
  float* V  = T + (size_t)MTOT * DIM;
  float* G  = V + (size_t)MTOT * DIM;
  float* u  = G + (size_t)DIM * DIM;
  float* w  = u + DIM;
  float* s0 = w + DIM;
  float* c  = s0 + 1;
  float* out = (float*)d_out;

  hipLaunchKernelGGL(k_gmat, dim3(DIM / 64, DIM / 64), dim3(256), 0, stream, Wq, Wk, G);
  hipLaunchKernelGGL(k_small, dim3(3), dim3(512), 0, stream, bq, Wk, Wq, bk, u, w, s0);
  hipLaunchKernelGGL(k_cvec, dim3(MTOT / 4), dim3(256), 0, stream, R, w, s0, c);
  hipLaunchKernelGGL(k_proj, dim3(MTOT / 128, DIM / 128, 2), dim3(256), 0, stream, R, G, u, Wv, bv, T, V);
  hipLaunchKernelGGL(k_attn, dim3(SEQ / 32, BATCH), dim3(256), 0, stream, T, R, V, c, W1, b1, W2, b2, out);
}

// Round 2
// 147.942 us; speedup vs baseline: 11.6660x; 11.6660x over previous
//
#include <hip/hip_runtime.h>
#include <math.h>

#define BATCH 8
#define SEQ 2048
#define DIM 512
#define MTOT (BATCH*SEQ)
#define HID 30

typedef short bf16x8 __attribute__((ext_vector_type(8)));
typedef float f32x4 __attribute__((ext_vector_type(4)));

__device__ __forceinline__ unsigned short f2bf(float f) {
  unsigned int u = __float_as_uint(f);
  unsigned int r = (u + 0x7FFFu + ((u >> 16) & 1u)) >> 16;  // RNE
  return (unsigned short)r;
}

__device__ __forceinline__ void gload_lds16(const void* g, void* l) {
  __builtin_amdgcn_global_load_lds((const __attribute__((address_space(1))) void*)g,
                                   (__attribute__((address_space(3))) void*)l, 16, 0, 0);
}

// ---- shared 128x128 tile GEMM core: C = A * B^T, A/B row-major [rows][K=512] bf16,
// BK=64, 4 waves (2x2), each wave 64x64 as 4x4 frags of 16x16x32.
// LDS tiles [128][64] bf16 with chunk-XOR swizzle (slot = chunk ^ (row&7)), staged via
// global_load_lds with pre-swizzled per-lane global source.
__device__ __forceinline__ void gemm128_core(const unsigned short* __restrict__ gA,
                                             const unsigned short* __restrict__ gB,
                                             char* smem, f32x4 (&acc)[4][4]) {
  const int t = threadIdx.x;
  const int lane = t & 63;
  const int w = t >> 6;
  const int wr = w >> 1, wc = w & 1;
  char* As = smem;
  char* Bs = smem + 16384;
  for (int kb = 0; kb < DIM; kb += 64) {
#pragma unroll
    for (int i = 0; i < 4; ++i) {
      int p = i * 256 + t;
      int row = p >> 3;
      int cg = (p & 7) ^ (row & 7);
      size_t goff = (size_t)row * DIM + kb + cg * 8;
      uint32_t ldsoff = (uint32_t)(i * 4096 + (t & 192) * 16);
      gload_lds16(gA + goff, As + ldsoff);
      gload_lds16(gB + goff, Bs + ldsoff);
    }
    asm volatile("s_waitcnt vmcnt(0)" ::: "memory");
    __syncthreads();
#pragma unroll
    for (int ks = 0; ks < 2; ++ks) {
      bf16x8 af[4], bfr[4];
      int kc = ks * 4 + (lane >> 4);
#pragma unroll
      for (int i = 0; i < 4; ++i) {
        int arow = wr * 64 + i * 16 + (lane & 15);
        af[i] = *(const bf16x8*)(As + arow * 128 + ((kc ^ (arow & 7)) << 4));
        int brow = wc * 64 + i * 16 + (lane & 15);
        bfr[i] = *(const bf16x8*)(Bs + brow * 128 + ((kc ^ (brow & 7)) << 4));
      }
#pragma unroll
      for (int i = 0; i < 4; ++i)
#pragma unroll
        for (int j = 0; j < 4; ++j)
          acc[i][j] = __builtin_amdgcn_mfma_f32_16x16x32_bf16(af[i], bfr[j], acc[i][j], 0, 0, 0);
    }
    __syncthreads();
  }
}

// ---------------- prep 1: u, w, s0, w12, c0 ----------------
__global__ void k_prep1(const float* __restrict__ bq, const float* __restrict__ Wk,
                        const float* __restrict__ Wq, const float* __restrict__ bk,
                        const float* __restrict__ W1, const float* __restrict__ W2,
                        const float* __restrict__ b1, const float* __restrict__ b2,
                        float* u, float* w, float* s0, float* w12, float* c0) {
  int t = threadIdx.x;
  if (blockIdx.x == 0) {
    float s = 0.f;
    for (int d = 0; d < DIM; ++d) s = fmaf(bq[d], Wk[(size_t)d * DIM + t], s);
    u[t] = s;
  } else if (blockIdx.x == 1) {
    float s = 0.f;
    for (int d = 0; d < DIM; ++d) s = fmaf(Wq[(size_t)d * DIM + t], bk[d], s);
    w[t] = s;
  } else if (blockIdx.x == 2) {
    __shared__ float red[512];
    red[t] = bq[t] * bk[t];
    __syncthreads();
    for (int o = 256; o > 0; o >>= 1) {
      if (t < o) red[t] += red[t + o];
      __syncthreads();
    }
    if (t == 0) {
      *s0 = red[0];
      float s = b2[0];
      for (int j = 0; j < HID; ++j) s = fmaf(W2[j], b1[j], s);
      *c0 = s;
    }
  } else {
    float s = 0.f;
    for (int j = 0; j < HID; ++j) s = fmaf(W2[j], W1[(size_t)j * DIM + t], s);
    w12[t] = s;
  }
}

// ---------------- prep 2: wv2 = Wv^T*w12, const1 = bv.w12 ----------------
__global__ void k_prep2(const float* __restrict__ Wv, const float* __restrict__ bv,
                        const float* __restrict__ w12, float* wv2, float* const1) {
  int t = threadIdx.x;
  if (blockIdx.x == 0) {
    float s = 0.f;
    for (int d = 0; d < DIM; ++d) s = fmaf(Wv[(size_t)d * DIM + t], w12[d], s);
    wv2[t] = s;
  } else {
    __shared__ float red[512];
    red[t] = bv[t] * w12[t];
    __syncthreads();
    for (int o = 256; o > 0; o >>= 1) {
      if (t < o) red[t] += red[t + o];
      __syncthreads();
    }
    if (t == 0) *const1 = red[0];
  }
}

// ---------------- Gt[c][k] = sum_d Wq[d][k] * Wk[d][c], bf16 ----------------
__global__ __launch_bounds__(256) void k_gmat(const float* __restrict__ Wq,
                                              const float* __restrict__ Wk,
                                              unsigned short* __restrict__ Gt) {
  __shared__ __align__(16) float As[16][68];
  __shared__ __align__(16) float Bs[16][68];
  int t = threadIdx.x;
  int tm = t & 15, tn = t >> 4;
  int q1b = blockIdx.x * 64, q2b = blockIdx.y * 64;
  int lk = t >> 4, lc = (t & 15) * 4;
  float acc[4][4] = {};
  for (int kb = 0; kb < DIM; kb += 16) {
    *(float4*)&As[lk][lc] = *(const float4*)&Wq[(size_t)(kb + lk) * DIM + q1b + lc];
    *(float4*)&Bs[lk][lc] = *(const float4*)&Wk[(size_t)(kb + lk) * DIM + q2b + lc];
    __syncthreads();
#pragma unroll
    for (int k = 0; k < 16; ++k) {
      float4 av = *(float4*)&As[k][tm * 4];
      float4 bv4 = *(float4*)&Bs[k][tn * 4];
      float a[4] = {av.x, av.y, av.z, av.w};
      float b[4] = {bv4.x, bv4.y, bv4.z, bv4.w};
#pragma unroll
      for (int i = 0; i < 4; ++i)
#pragma unroll
        for (int j = 0; j < 4; ++j) acc[i][j] = fmaf(a[i], b[j], acc[i][j]);
    }
    __syncthreads();
  }
  // store transposed: Gt[q2][q1]
#pragma unroll
  for (int i = 0; i < 4; ++i)
#pragma unroll
    for (int j = 0; j < 4; ++j)
      Gt[(size_t)(q2b + tn * 4 + j) * DIM + (q1b + tm * 4 + i)] = f2bf(acc[i][j]);
}

// ---------------- c[n] = R.w + s0; vw[n] = R.wv2 + const1; Rb16 = bf16(R) ----------------
__global__ __launch_bounds__(256) void k_cvec2(const float* __restrict__ R,
                                               const float* __restrict__ w,
                                               const float* __restrict__ wv2,
                                               const float* __restrict__ s0,
                                               const float* __restrict__ const1,
                                               float* __restrict__ c, float* __restrict__ vw,
                                               unsigned short* __restrict__ Rb16) {
  int wave = threadIdx.x >> 6, lane = threadIdx.x & 63;
  size_t n = (size_t)blockIdx.x * 4 + wave;
  const float* p = &R[n * DIM + lane * 8];
  float4 r0 = *(const float4*)p;
  float4 r1 = *(const float4*)(p + 4);
  ushort4 lo, hi;
  lo.x = f2bf(r0.x); lo.y = f2bf(r0.y); lo.z = f2bf(r0.z); lo.w = f2bf(r0.w);
  hi.x = f2bf(r1.x); hi.y = f2bf(r1.y); hi.z = f2bf(r1.z); hi.w = f2bf(r1.w);
  *(ushort4*)&Rb16[n * DIM + lane * 8] = lo;
  *(ushort4*)&Rb16[n * DIM + lane * 8 + 4] = hi;
  float4 w0 = *(const float4*)&w[lane * 8];
  float4 w1 = *(const float4*)&w[lane * 8 + 4];
  float4 v0 = *(const float4*)&wv2[lane * 8];
  float4 v1 = *(const float4*)&wv2[lane * 8 + 4];
  float sc = r0.x * w0.x + r0.y * w0.y + r0.z * w0.z + r0.w * w0.w +
             r1.x * w1.x + r1.y * w1.y + r1.z * w1.z + r1.w * w1.w;
  float sv = r0.x * v0.x + r0.y * v0.y + r0.z * v0.z + r0.w * v0.w +
             r1.x * v1.x + r1.y * v1.y + r1.z * v1.z + r1.w * v1.w;
#pragma unroll
  for (int o = 32; o > 0; o >>= 1) { sc += __shfl_xor(sc, o); sv += __shfl_xor(sv, o); }
  if (lane == 0) { c[n] = sc + s0[0]; vw[n] = sv + const1[0]; }
}

// ---------------- T = R @ Gt^T + u, output bf16 ----------------
__global__ __launch_bounds__(256) void k_projT(const unsigned short* __restrict__ Rb16,
                                               const unsigned short* __restrict__ Gt,
                                               const float* __restrict__ u,
                                               unsigned short* __restrict__ Tb16) {
  __shared__ __align__(16) char smem[32768];
  __shared__ float u_lds[128];
  int t = threadIdx.x;
  size_t rowb = (size_t)blockIdx.x * 128;
  int colb = blockIdx.y * 128;
  if (t < 128) u_lds[t] = u[colb + t];
  f32x4 acc[4][4] = {};
  gemm128_core(Rb16 + rowb * DIM, Gt + (size_t)colb * DIM, smem, acc);
  int lane = t & 63, w = t >> 6, wr = w >> 1, wc = w & 1;
#pragma unroll
  for (int i = 0; i < 4; ++i)
#pragma unroll
    for (int j = 0; j < 4; ++j)
#pragma unroll
      for (int r = 0; r < 4; ++r) {
        int row = wr * 64 + i * 16 + (lane >> 4) * 4 + r;
        int col = wc * 64 + j * 16 + (lane & 15);
        Tb16[(rowb + row) * DIM + colb + col] = f2bf(acc[i][j][r] + u_lds[col]);
      }
}

// ---------------- QK^T + exp + fused s1/den partial reduction ----------------
__global__ __launch_bounds__(256) void k_qk(const unsigned short* __restrict__ Tb16,
                                            const unsigned short* __restrict__ Rb16,
                                            const float* __restrict__ cvec,
                                            const float* __restrict__ vw,
                                            float* __restrict__ part_s1,
                                            float* __restrict__ part_den) {
  __shared__ __align__(16) char smem[32768];
  __shared__ float c_lds[128], vw_lds[128];
  __shared__ float red_s1[2][128], red_den[2][128];
  int t = threadIdx.x;
  int nb = blockIdx.x * 128;
  int mb = blockIdx.y * 128;
  int b = blockIdx.z;
  if (t < 128) {
    c_lds[t] = cvec[b * SEQ + nb + t];
    vw_lds[t] = vw[b * SEQ + mb + t];
  }
  const unsigned short* gA = Tb16 + ((size_t)b * SEQ + nb) * DIM;
  const unsigned short* gB = Rb16 + ((size_t)b * SEQ + mb) * DIM;
  f32x4 acc[4][4] = {};
  gemm128_core(gA, gB, smem, acc);
  int lane = t & 63, w = t >> 6, wr = w >> 1, wc = w & 1;
  const float rs = 0.044194173824159216f;  // 1/sqrt(512)
  float vwl[4];
#pragma unroll
  for (int j = 0; j < 4; ++j) vwl[j] = vw_lds[wc * 64 + j * 16 + (lane & 15)];
  float s1p[4][4] = {}, dnp[4][4] = {};
#pragma unroll
  for (int i = 0; i < 4; ++i) {
    float cv[4];
#pragma unroll
    for (int r = 0; r < 4; ++r) cv[r] = c_lds[wr * 64 + i * 16 + (lane >> 4) * 4 + r];
#pragma unroll
    for (int j = 0; j < 4; ++j)
#pragma unroll
      for (int r = 0; r < 4; ++r) {
        float e = __expf((acc[i][j][r] + cv[r]) * rs);
        s1p[i][r] = fmaf(e, vwl[j], s1p[i][r]);
        dnp[i][r] += e;
      }
  }
#pragma unroll
  for (int i = 0; i < 4; ++i)
#pragma unroll
    for (int r = 0; r < 4; ++r) {
      float a = s1p[i][r], d = dnp[i][r];
#pragma unroll
      for (int m = 1; m < 16; m <<= 1) { a += __shfl_xor(a, m); d += __shfl_xor(d, m); }
      if ((lane & 15) == 0) {
        int rl = wr * 64 + i * 16 + (lane >> 4) * 4 + r;
        red_s1[wc][rl] = a;
        red_den[wc][rl] = d;
      }
    }
  __syncthreads();
  if (t < 128) {
    size_t o = ((size_t)b * 16 + blockIdx.y) * SEQ + nb + t;
    part_s1[o] = red_s1[0][t] + red_s1[1][t];
    part_den[o] = red_den[0][t] + red_den[1][t];
  }
}

// ---------------- final: winner = s1/den + c0 ----------------
__global__ void k_final(const float* __restrict__ part_s1, const float* __restrict__ part_den,
                        const float* __restrict__ c0, float* __restrict__ out) {
  int n = blockIdx.x * 256 + threadIdx.x;
  int b = n >> 11, nn = n & 2047;
  float s1 = 0.f, dn = 0.f;
#pragma unroll
  for (int mbi = 0; mbi < 16; ++mbi) {
    size_t o = ((size_t)b * 16 + mbi) * SEQ + nn;
    s1 += part_s1[o];
    dn += part_den[o];
  }
  out[n] = s1 / dn + c0[0];
}

extern "C" void kernel_launch(void* const* d_in, const int* in_sizes, int n_in,
                              void* d_out, int out_size, void* d_ws, size_t ws_size,
                              hipStream_t stream) {
  const float* R  = (const float*)d_in[0];
  const float* Wq = (const float*)d_in[1];
  const float* bq = (const float*)d_in[2];
  const float* Wk = (const float*)d_in[3];
  const float* bk = (const float*)d_in[4];
  const float* Wv = (const float*)d_in[5];
  const float* bv = (const float*)d_in[6];
  const float* W1 = (const float*)d_in[7];
  const float* b1 = (const float*)d_in[8];
  const float* W2 = (const float*)d_in[9];
  const float* b2 = (const float*)d_in[10];
  float* out = (float*)d_out;

  char* p = (char*)d_ws;
  unsigned short* Rb16 = (unsigned short*)p; p += (size_t)MTOT * DIM * 2;
  unsigned short* Tb16 = (unsigned short*)p; p += (size_t)MTOT * DIM * 2;
  unsigned short* Gt   = (unsigned short*)p; p += (size_t)DIM * DIM * 2;
  float* part_s1 = (float*)p; p += (size_t)BATCH * 16 * SEQ * 4;
  float* part_den = (float*)p; p += (size_t)BATCH * 16 * SEQ * 4;
  float* u   = (float*)p; p += DIM * 4;
  float* w   = (float*)p; p += DIM * 4;
  float* w12 = (float*)p; p += DIM * 4;
  float* wv2 = (float*)p; p += DIM * 4;
  float* c   = (float*)p; p += MTOT * 4;
  float* vw  = (float*)p; p += MTOT * 4;
  float* s0  = (float*)p; p += 4;
  float* c0  = (float*)p; p += 4;
  float* const1 = (float*)p; p += 4;

  hipLaunchKernelGGL(k_prep1, dim3(4), dim3(512), 0, stream, bq, Wk, Wq, bk, W1, W2, b1, b2,
                     u, w, s0, w12, c0);
  hipLaunchKernelGGL(k_prep2, dim3(2), dim3(512), 0, stream, Wv, bv, w12, wv2, const1);
  hipLaunchKernelGGL(k_gmat, dim3(8, 8), dim3(256), 0, stream, Wq, Wk, Gt);
  hipLaunchKernelGGL(k_cvec2, dim3(MTOT / 4), dim3(256), 0, stream, R, w, wv2, s0, const1,
                     c, vw, Rb16);
  hipLaunchKernelGGL(k_projT, dim3(MTOT / 128, DIM / 128), dim3(256), 0, stream,
                     Rb16, Gt, u, Tb16);
  hipLaunchKernelGGL(k_qk, dim3(SEQ / 128, SEQ / 128, BATCH), dim3(256), 0, stream,
                     Tb16, Rb16, c, vw, part_s1, part_den);
  hipLaunchKernelGGL(k_final, dim3(MTOT / 256), dim3(256), 0, stream,
                     part_s1, part_den, c0, out);
}

// Round 3
// 138.408 us; speedup vs baseline: 12.4696x; 1.0689x over previous
//
#include <hip/hip_runtime.h>
#include <math.h>

#define BATCH 8
#define SEQ 2048
#define DIM 512
#define MTOT (BATCH*SEQ)
#define HID 30

typedef short bf16x8 __attribute__((ext_vector_type(8)));
typedef float f32x4 __attribute__((ext_vector_type(4)));

__device__ __forceinline__ unsigned short f2bf(float f) {
  unsigned int u = __float_as_uint(f);
  unsigned int r = (u + 0x7FFFu + ((u >> 16) & 1u)) >> 16;  // RNE
  return (unsigned short)r;
}

__device__ __forceinline__ void gload_lds16(const void* g, void* l) {
  __builtin_amdgcn_global_load_lds((const __attribute__((address_space(1))) void*)g,
                                   (__attribute__((address_space(3))) void*)l, 16, 0, 0);
}

// ---- 128x128 tile GEMM core (round-2 verified), used by k_projT ----
__device__ __forceinline__ void gemm128_core(const unsigned short* __restrict__ gA,
                                             const unsigned short* __restrict__ gB,
                                             char* smem, f32x4 (&acc)[4][4]) {
  const int t = threadIdx.x;
  const int lane = t & 63;
  const int w = t >> 6;
  const int wr = w >> 1, wc = w & 1;
  char* As = smem;
  char* Bs = smem + 16384;
  for (int kb = 0; kb < DIM; kb += 64) {
#pragma unroll
    for (int i = 0; i < 4; ++i) {
      int p = i * 256 + t;
      int row = p >> 3;
      int cg = (p & 7) ^ (row & 7);
      size_t goff = (size_t)row * DIM + kb + cg * 8;
      uint32_t ldsoff = (uint32_t)(i * 4096 + (t & 192) * 16);
      gload_lds16(gA + goff, As + ldsoff);
      gload_lds16(gB + goff, Bs + ldsoff);
    }
    asm volatile("s_waitcnt vmcnt(0)" ::: "memory");
    __syncthreads();
#pragma unroll
    for (int ks = 0; ks < 2; ++ks) {
      bf16x8 af[4], bfr[4];
      int kc = ks * 4 + (lane >> 4);
#pragma unroll
      for (int i = 0; i < 4; ++i) {
        int arow = wr * 64 + i * 16 + (lane & 15);
        af[i] = *(const bf16x8*)(As + arow * 128 + ((kc ^ (arow & 7)) << 4));
        int brow = wc * 64 + i * 16 + (lane & 15);
        bfr[i] = *(const bf16x8*)(Bs + brow * 128 + ((kc ^ (brow & 7)) << 4));
      }
#pragma unroll
      for (int i = 0; i < 4; ++i)
#pragma unroll
        for (int j = 0; j < 4; ++j)
          acc[i][j] = __builtin_amdgcn_mfma_f32_16x16x32_bf16(af[i], bfr[j], acc[i][j], 0, 0, 0);
    }
    __syncthreads();
  }
}

// ---------------- prep 1: u, w, s0, w12, c0 ----------------
__global__ void k_prep1(const float* __restrict__ bq, const float* __restrict__ Wk,
                        const float* __restrict__ Wq, const float* __restrict__ bk,
                        const float* __restrict__ W1, const float* __restrict__ W2,
                        const float* __restrict__ b1, const float* __restrict__ b2,
                        float* u, float* w, float* s0, float* w12, float* c0) {
  int t = threadIdx.x;
  if (blockIdx.x == 0) {
    float s = 0.f;
    for (int d = 0; d < DIM; ++d) s = fmaf(bq[d], Wk[(size_t)d * DIM + t], s);
    u[t] = s;
  } else if (blockIdx.x == 1) {
    float s = 0.f;
    for (int d = 0; d < DIM; ++d) s = fmaf(Wq[(size_t)d * DIM + t], bk[d], s);
    w[t] = s;
  } else if (blockIdx.x == 2) {
    __shared__ float red[512];
    red[t] = bq[t] * bk[t];
    __syncthreads();
    for (int o = 256; o > 0; o >>= 1) {
      if (t < o) red[t] += red[t + o];
      __syncthreads();
    }
    if (t == 0) {
      *s0 = red[0];
      float s = b2[0];
      for (int j = 0; j < HID; ++j) s = fmaf(W2[j], b1[j], s);
      *c0 = s;
    }
  } else {
    float s = 0.f;
    for (int j = 0; j < HID; ++j) s = fmaf(W2[j], W1[(size_t)j * DIM + t], s);
    w12[t] = s;
  }
}

// ---------------- prep 2: wv2 = Wv^T*w12, const1 = bv.w12 ----------------
__global__ void k_prep2(const float* __restrict__ Wv, const float* __restrict__ bv,
                        const float* __restrict__ w12, float* wv2, float* const1) {
  int t = threadIdx.x;
  if (blockIdx.x == 0) {
    float s = 0.f;
    for (int d = 0; d < DIM; ++d) s = fmaf(Wv[(size_t)d * DIM + t], w12[d], s);
    wv2[t] = s;
  } else {
    __shared__ float red[512];
    red[t] = bv[t] * w12[t];
    __syncthreads();
    for (int o = 256; o > 0; o >>= 1) {
      if (t < o) red[t] += red[t + o];
      __syncthreads();
    }
    if (t == 0) *const1 = red[0];
  }
}

// ---------------- Gt[c][k] = sum_d Wq[d][k] * Wk[d][c], bf16 ----------------
__global__ __launch_bounds__(256) void k_gmat(const float* __restrict__ Wq,
                                              const float* __restrict__ Wk,
                                              unsigned short* __restrict__ Gt) {
  __shared__ __align__(16) float As[16][68];
  __shared__ __align__(16) float Bs[16][68];
  int t = threadIdx.x;
  int tm = t & 15, tn = t >> 4;
  int q1b = blockIdx.x * 64, q2b = blockIdx.y * 64;
  int lk = t >> 4, lc = (t & 15) * 4;
  float acc[4][4] = {};
  for (int kb = 0; kb < DIM; kb += 16) {
    *(float4*)&As[lk][lc] = *(const float4*)&Wq[(size_t)(kb + lk) * DIM + q1b + lc];
    *(float4*)&Bs[lk][lc] = *(const float4*)&Wk[(size_t)(kb + lk) * DIM + q2b + lc];
    __syncthreads();
#pragma unroll
    for (int k = 0; k < 16; ++k) {
      float4 av = *(float4*)&As[k][tm * 4];
      float4 bv4 = *(float4*)&Bs[k][tn * 4];
      float a[4] = {av.x, av.y, av.z, av.w};
      float b[4] = {bv4.x, bv4.y, bv4.z, bv4.w};
#pragma unroll
      for (int i = 0; i < 4; ++i)
#pragma unroll
        for (int j = 0; j < 4; ++j) acc[i][j] = fmaf(a[i], b[j], acc[i][j]);
    }
    __syncthreads();
  }
#pragma unroll
  for (int i = 0; i < 4; ++i)
#pragma unroll
    for (int j = 0; j < 4; ++j)
      Gt[(size_t)(q2b + tn * 4 + j) * DIM + (q1b + tm * 4 + i)] = f2bf(acc[i][j]);
}

// ---------------- c[n] = R.w + s0; vw[n] = R.wv2 + const1; Rb16 = bf16(R) ----------------
__global__ __launch_bounds__(256) void k_cvec2(const float* __restrict__ R,
                                               const float* __restrict__ w,
                                               const float* __restrict__ wv2,
                                               const float* __restrict__ s0,
                                               const float* __restrict__ const1,
                                               float* __restrict__ c, float* __restrict__ vw,
                                               unsigned short* __restrict__ Rb16) {
  int wave = threadIdx.x >> 6, lane = threadIdx.x & 63;
  size_t n = (size_t)blockIdx.x * 4 + wave;
  const float* p = &R[n * DIM + lane * 8];
  float4 r0 = *(const float4*)p;
  float4 r1 = *(const float4*)(p + 4);
  ushort4 lo, hi;
  lo.x = f2bf(r0.x); lo.y = f2bf(r0.y); lo.z = f2bf(r0.z); lo.w = f2bf(r0.w);
  hi.x = f2bf(r1.x); hi.y = f2bf(r1.y); hi.z = f2bf(r1.z); hi.w = f2bf(r1.w);
  *(ushort4*)&Rb16[n * DIM + lane * 8] = lo;
  *(ushort4*)&Rb16[n * DIM + lane * 8 + 4] = hi;
  float4 w0 = *(const float4*)&w[lane * 8];
  float4 w1 = *(const float4*)&w[lane * 8 + 4];
  float4 v0 = *(const float4*)&wv2[lane * 8];
  float4 v1 = *(const float4*)&wv2[lane * 8 + 4];
  float sc = r0.x * w0.x + r0.y * w0.y + r0.z * w0.z + r0.w * w0.w +
             r1.x * w1.x + r1.y * w1.y + r1.z * w1.z + r1.w * w1.w;
  float sv = r0.x * v0.x + r0.y * v0.y + r0.z * v0.z + r0.w * v0.w +
             r1.x * v1.x + r1.y * v1.y + r1.z * v1.z + r1.w * v1.w;
#pragma unroll
  for (int o = 32; o > 0; o >>= 1) { sc += __shfl_xor(sc, o); sv += __shfl_xor(sv, o); }
  if (lane == 0) { c[n] = sc + s0[0]; vw[n] = sv + const1[0]; }
}

// ---------------- T = R @ Gt^T + u, output bf16 ----------------
__global__ __launch_bounds__(256) void k_projT(const unsigned short* __restrict__ Rb16,
                                               const unsigned short* __restrict__ Gt,
                                               const float* __restrict__ u,
                                               unsigned short* __restrict__ Tb16) {
  __shared__ __align__(16) char smem[32768];
  __shared__ float u_lds[128];
  int t = threadIdx.x;
  size_t rowb = (size_t)blockIdx.x * 128;
  int colb = blockIdx.y * 128;
  if (t < 128) u_lds[t] = u[colb + t];
  f32x4 acc[4][4] = {};
  gemm128_core(Rb16 + rowb * DIM, Gt + (size_t)colb * DIM, smem, acc);
  int lane = t & 63, w = t >> 6, wr = w >> 1, wc = w & 1;
#pragma unroll
  for (int i = 0; i < 4; ++i)
#pragma unroll
    for (int j = 0; j < 4; ++j)
#pragma unroll
      for (int r = 0; r < 4; ++r) {
        int row = wr * 64 + i * 16 + (lane >> 4) * 4 + r;
        int col = wc * 64 + j * 16 + (lane & 15);
        Tb16[(rowb + row) * DIM + colb + col] = f2bf(acc[i][j][r] + u_lds[col]);
      }
}

// ---------------- QK^T + exp + fused s1/den partials ----------------
// 256x256 tile, BK=32, 8 waves (2x4), triple-buffered LDS, counted vmcnt(4).
__global__ __launch_bounds__(512, 2) void k_qk(const unsigned short* __restrict__ Tb16,
                                               const unsigned short* __restrict__ Rb16,
                                               const float* __restrict__ cvec,
                                               const float* __restrict__ vw,
                                               float* __restrict__ part_s1,
                                               float* __restrict__ part_den) {
  __shared__ __align__(16) char smem[98304];  // 3 bufs x (A[256][32] + B[256][32]) bf16
  __shared__ float c_lds[256], vw_lds[256];
  __shared__ float red_s1[4][256], red_den[4][256];

  const int t = threadIdx.x;
  const int lane = t & 63;
  const int w = t >> 6;   // 0..7
  const int wr = w >> 2;  // 0..1 -> rows
  const int wc = w & 3;   // 0..3 -> cols

  // XCD swizzle: each XCD gets one full batch (T+R panels fit 4MB L2)
  int orig = blockIdx.x;
  int wgid = (orig & 7) * 64 + (orig >> 3);
  int b = wgid >> 6;
  int nb = ((wgid >> 3) & 7) * 256;
  int mb = (wgid & 7) * 256;

  const unsigned short* gA = Tb16 + ((size_t)b * SEQ + nb) * DIM;
  const unsigned short* gB = Rb16 + ((size_t)b * SEQ + mb) * DIM;

  if (t < 256) {
    c_lds[t] = cvec[b * SEQ + nb + t];
    vw_lds[t] = vw[b * SEQ + mb + t];
  }

  // stage K-tile kt (32 k-cols) of A and B into buffer `buf` (4 loads/thread)
  auto stage = [&](int buf, int kt) {
#pragma unroll
    for (int q = 0; q < 2; ++q) {
      int p = q * 512 + t;
      int row = p >> 2;
      int cg = (p & 3) ^ ((row ^ (row >> 2)) & 3);
      size_t go = (size_t)row * DIM + kt * 32 + cg * 8;
      uint32_t lo = (uint32_t)(q * 8192 + (t & 448) * 16);
      gload_lds16(gA + go, smem + buf * 32768 + lo);
      gload_lds16(gB + go, smem + buf * 32768 + 16384 + lo);
    }
  };

  // prologue: tiles 0,1 in flight; wait tile 0
  stage(0, 0);
  stage(1, 1);
  asm volatile("s_waitcnt vmcnt(4)" ::: "memory");
  __builtin_amdgcn_s_barrier();
  asm volatile("" ::: "memory");

  f32x4 acc[8][4] = {};
  const int kc = lane >> 4;
  const int lr = lane & 15;

#pragma unroll
  for (int kt = 0; kt < 16; ++kt) {
    const int cb = kt % 3;
    const int pb = (kt + 2) % 3;
    const int src = (kt + 2 < 16) ? (kt + 2) : 15;  // dummy keeps vmcnt uniform
    stage(pb, src);
    const char* Ab = smem + cb * 32768;
    const char* Bb = Ab + 16384;
    bf16x8 bfr[4];
#pragma unroll
    for (int j = 0; j < 4; ++j) {
      int brow = wc * 64 + j * 16 + lr;
      bfr[j] = *(const bf16x8*)(Bb + brow * 64 + ((kc ^ ((brow ^ (brow >> 2)) & 3)) << 4));
    }
    bf16x8 af[4];
#pragma unroll
    for (int i = 0; i < 4; ++i) {
      int arow = wr * 128 + i * 16 + lr;
      af[i] = *(const bf16x8*)(Ab + arow * 64 + ((kc ^ ((arow ^ (arow >> 2)) & 3)) << 4));
    }
    __builtin_amdgcn_s_setprio(1);
#pragma unroll
    for (int i = 0; i < 4; ++i)
#pragma unroll
      for (int j = 0; j < 4; ++j)
        acc[i][j] = __builtin_amdgcn_mfma_f32_16x16x32_bf16(af[i], bfr[j], acc[i][j], 0, 0, 0);
    __builtin_amdgcn_s_setprio(0);
#pragma unroll
    for (int i = 0; i < 4; ++i) {
      int arow = wr * 128 + (i + 4) * 16 + lr;
      af[i] = *(const bf16x8*)(Ab + arow * 64 + ((kc ^ ((arow ^ (arow >> 2)) & 3)) << 4));
    }
    __builtin_amdgcn_s_setprio(1);
#pragma unroll
    for (int i = 0; i < 4; ++i)
#pragma unroll
      for (int j = 0; j < 4; ++j)
        acc[i + 4][j] = __builtin_amdgcn_mfma_f32_16x16x32_bf16(af[i], bfr[j], acc[i + 4][j], 0, 0, 0);
    __builtin_amdgcn_s_setprio(0);
    asm volatile("s_waitcnt vmcnt(4)" ::: "memory");
    __builtin_amdgcn_s_barrier();
    asm volatile("" ::: "memory");
  }

  // epilogue: e = exp((S+c)*rs); s1 += e*vw; den += e; reduce across 16 col-lanes
  const float rs = 0.044194173824159216f;  // 1/sqrt(512)
  float vwl[4];
#pragma unroll
  for (int j = 0; j < 4; ++j) vwl[j] = vw_lds[wc * 64 + j * 16 + lr];
#pragma unroll
  for (int i = 0; i < 8; ++i) {
#pragma unroll
    for (int r = 0; r < 4; ++r) {
      int rl = wr * 128 + i * 16 + (lane >> 4) * 4 + r;
      float cv = c_lds[rl];
      float sa = 0.f, sd = 0.f;
#pragma unroll
      for (int j = 0; j < 4; ++j) {
        float e = __expf((acc[i][j][r] + cv) * rs);
        sa = fmaf(e, vwl[j], sa);
        sd += e;
      }
#pragma unroll
      for (int m = 1; m < 16; m <<= 1) { sa += __shfl_xor(sa, m); sd += __shfl_xor(sd, m); }
      if (lr == 0) { red_s1[wc][rl] = sa; red_den[wc][rl] = sd; }
    }
  }
  __syncthreads();
  if (t < 256) {
    size_t o = ((size_t)b * 8 + (mb >> 8)) * SEQ + nb + t;
    part_s1[o] = red_s1[0][t] + red_s1[1][t] + red_s1[2][t] + red_s1[3][t];
    part_den[o] = red_den[0][t] + red_den[1][t] + red_den[2][t] + red_den[3][t];
  }
}

// ---------------- final: winner = s1/den + c0 ----------------
__global__ void k_final(const float* __restrict__ part_s1, const float* __restrict__ part_den,
                        const float* __restrict__ c0, float* __restrict__ out) {
  int n = blockIdx.x * 256 + threadIdx.x;
  int b = n >> 11, nn = n & 2047;
  float s1 = 0.f, dn = 0.f;
#pragma unroll
  for (int mbi = 0; mbi < 8; ++mbi) {
    size_t o = ((size_t)b * 8 + mbi) * SEQ + nn;
    s1 += part_s1[o];
    dn += part_den[o];
  }
  out[n] = s1 / dn + c0[0];
}

extern "C" void kernel_launch(void* const* d_in, const int* in_sizes, int n_in,
                              void* d_out, int out_size, void* d_ws, size_t ws_size,
                              hipStream_t stream) {
  const float* R  = (const float*)d_in[0];
  const float* Wq = (const float*)d_in[1];
  const float* bq = (const float*)d_in[2];
  const float* Wk = (const float*)d_in[3];
  const float* bk = (const float*)d_in[4];
  const float* Wv = (const float*)d_in[5];
  const float* bv = (const float*)d_in[6];
  const float* W1 = (const float*)d_in[7];
  const float* b1 = (const float*)d_in[8];
  const float* W2 = (const float*)d_in[9];
  const float* b2 = (const float*)d_in[10];
  float* out = (float*)d_out;

  char* p = (char*)d_ws;
  unsigned short* Rb16 = (unsigned short*)p; p += (size_t)MTOT * DIM * 2;
  unsigned short* Tb16 = (unsigned short*)p; p += (size_t)MTOT * DIM * 2;
  unsigned short* Gt   = (unsigned short*)p; p += (size_t)DIM * DIM * 2;
  float* part_s1 = (float*)p; p += (size_t)BATCH * 8 * SEQ * 4;
  float* part_den = (float*)p; p += (size_t)BATCH * 8 * SEQ * 4;
  float* u   = (float*)p; p += DIM * 4;
  float* w   = (float*)p; p += DIM * 4;
  float* w12 = (float*)p; p += DIM * 4;
  float* wv2 = (float*)p; p += DIM * 4;
  float* c   = (float*)p; p += MTOT * 4;
  float* vw  = (float*)p; p += MTOT * 4;
  float* s0  = (float*)p; p += 4;
  float* c0  = (float*)p; p += 4;
  float* const1 = (float*)p; p += 4;

  hipLaunchKernelGGL(k_prep1, dim3(4), dim3(512), 0, stream, bq, Wk, Wq, bk, W1, W2, b1, b2,
                     u, w, s0, w12, c0);
  hipLaunchKernelGGL(k_prep2, dim3(2), dim3(512), 0, stream, Wv, bv, w12, wv2, const1);
  hipLaunchKernelGGL(k_gmat, dim3(8, 8), dim3(256), 0, stream, Wq, Wk, Gt);
  hipLaunchKernelGGL(k_cvec2, dim3(MTOT / 4), dim3(256), 0, stream, R, w, wv2, s0, const1,
                     c, vw, Rb16);
  hipLaunchKernelGGL(k_projT, dim3(MTOT / 128, DIM / 128), dim3(256), 0, stream,
                     Rb16, Gt, u, Tb16);
  hipLaunchKernelGGL(k_qk, dim3(512), dim3(512), 0, stream,
                     Tb16, Rb16, c, vw, part_s1, part_den);
  hipLaunchKernelGGL(k_final, dim3(MTOT / 256), dim3(256), 0, stream,
                     part_s1, part_den, c0, out);
}

// Round 4
// 114.072 us; speedup vs baseline: 15.1299x; 1.2133x over previous
//
#include <hip/hip_runtime.h>
#include <math.h>

#define BATCH 8
#define SEQ 2048
#define DIM 512
#define MTOT (BATCH*SEQ)
#define HID 30

typedef short bf16x8 __attribute__((ext_vector_type(8)));
typedef float f32x4 __attribute__((ext_vector_type(4)));

__device__ __forceinline__ unsigned short f2bf(float f) {
  unsigned int u = __float_as_uint(f);
  unsigned int r = (u + 0x7FFFu + ((u >> 16) & 1u)) >> 16;  // RNE
  return (unsigned short)r;
}
__device__ __forceinline__ float bf2f(unsigned short u) {
  return __uint_as_float((unsigned int)u << 16);
}

__device__ __forceinline__ void gload_lds16(const void* g, void* l) {
  __builtin_amdgcn_global_load_lds((const __attribute__((address_space(1))) void*)g,
                                   (__attribute__((address_space(3))) void*)l, 16, 0, 0);
}

// ---- 256x256 tile GEMM core: C = A * B^T, A/B row-major [256 rows][K=512] bf16.
// BK=32, 8 waves (2 row x 4 col), 4 LDS buffers (prefetch distance 3, vmcnt(8)).
// Unified macro-row layout: row r = [A chunks s0..3 | B chunks s4..7], 128 B stride,
// physical slot = s ^ (r&7)  (round-2-verified zero-conflict geometry).
// Staged via global_load_lds (linear dest); per-lane source picks gA/gB + inverse swizzle.
__device__ __forceinline__ void gemm256_core(const unsigned short* __restrict__ gA,
                                             const unsigned short* __restrict__ gB,
                                             char* smem, f32x4 (&acc)[8][4]) {
  const int t = threadIdx.x;
  const int lane = t & 63;
  const int w = t >> 6;
  const int wr = w >> 2, wc = w & 3;
  const int lr = lane & 15, kc = lane >> 4;
  const int srow = t >> 3;                       // staging row base (0..63)
  const int ss = (t & 7) ^ (srow & 7);           // original slot for this dest chunk
  const unsigned short* gsrc = (ss < 4 ? gA : gB) + (size_t)srow * DIM + (ss & 3) * 8;
  const uint32_t dbase = (uint32_t)(t & 448) * 16;

  auto stage = [&](int buf, int kt) {
#pragma unroll
    for (int q = 0; q < 4; ++q)
      gload_lds16(gsrc + (size_t)(q * 64) * DIM + kt * 32,
                  smem + buf * 32768 + q * 8192 + dbase);
  };

  stage(0, 0); stage(1, 1); stage(2, 2);
  asm volatile("s_waitcnt vmcnt(8)" ::: "memory");
  __builtin_amdgcn_s_barrier();
  asm volatile("" ::: "memory");

#pragma unroll
  for (int kt = 0; kt < 16; ++kt) {
    stage((kt + 3) & 3, (kt + 3 < 16) ? (kt + 3) : 15);  // dummy tail keeps vmcnt uniform
    const char* Ab = smem + (kt & 3) * 32768;
    bf16x8 bfr[4], af[4];
#pragma unroll
    for (int j = 0; j < 4; ++j) {
      int r = wc * 64 + j * 16 + lr;
      bfr[j] = *(const bf16x8*)(Ab + r * 128 + (((4 + kc) ^ (r & 7)) << 4));
    }
#pragma unroll
    for (int i = 0; i < 4; ++i) {
      int r = wr * 128 + i * 16 + lr;
      af[i] = *(const bf16x8*)(Ab + r * 128 + ((kc ^ (r & 7)) << 4));
    }
    __builtin_amdgcn_s_setprio(1);
#pragma unroll
    for (int i = 0; i < 4; ++i)
#pragma unroll
      for (int j = 0; j < 4; ++j)
        acc[i][j] = __builtin_amdgcn_mfma_f32_16x16x32_bf16(af[i], bfr[j], acc[i][j], 0, 0, 0);
    __builtin_amdgcn_s_setprio(0);
#pragma unroll
    for (int i = 0; i < 4; ++i) {
      int r = wr * 128 + (i + 4) * 16 + lr;
      af[i] = *(const bf16x8*)(Ab + r * 128 + ((kc ^ (r & 7)) << 4));
    }
    __builtin_amdgcn_s_setprio(1);
#pragma unroll
    for (int i = 0; i < 4; ++i)
#pragma unroll
      for (int j = 0; j < 4; ++j)
        acc[i + 4][j] = __builtin_amdgcn_mfma_f32_16x16x32_bf16(af[i], bfr[j], acc[i + 4][j], 0, 0, 0);
    __builtin_amdgcn_s_setprio(0);
    asm volatile("s_waitcnt vmcnt(8)" ::: "memory");
    __builtin_amdgcn_s_barrier();
    asm volatile("" ::: "memory");
  }
}

// ---------------- k_setup: gmat (blocks 0-63) | wv2/consts (64) | u (65) | R->bf16 (66+) ----
__global__ __launch_bounds__(256) void k_setup(
    const float* __restrict__ R, const float* __restrict__ Wq, const float* __restrict__ Wk,
    const float* __restrict__ Wv, const float* __restrict__ bq, const float* __restrict__ bv,
    const float* __restrict__ W1, const float* __restrict__ b1,
    const float* __restrict__ W2, const float* __restrict__ b2,
    unsigned short* __restrict__ Gt, unsigned short* __restrict__ Rb16,
    float* __restrict__ u, float* __restrict__ wv2, float* __restrict__ consts) {
  __shared__ __align__(16) float As[16][68];
  __shared__ __align__(16) float Bs[16][68];
  __shared__ float w12s[512];
  __shared__ float red[256];
  const int bid = blockIdx.x;
  const int t = threadIdx.x;

  if (bid >= 66) {  // R -> bf16 conversion
    size_t base = ((size_t)(bid - 66) * 256 + t) * 8;
    float4 r0 = *(const float4*)&R[base];
    float4 r1 = *(const float4*)&R[base + 4];
    ushort4 lo, hi;
    lo.x = f2bf(r0.x); lo.y = f2bf(r0.y); lo.z = f2bf(r0.z); lo.w = f2bf(r0.w);
    hi.x = f2bf(r1.x); hi.y = f2bf(r1.y); hi.z = f2bf(r1.z); hi.w = f2bf(r1.w);
    *(ushort4*)&Rb16[base] = lo;
    *(ushort4*)&Rb16[base + 4] = hi;
    return;
  }
  if (bid == 64) {  // w12 -> wv2, const1, c0
    for (int q = t; q < DIM; q += 256) {
      float s = 0.f;
      for (int j = 0; j < HID; ++j) s = fmaf(W2[j], W1[(size_t)j * DIM + q], s);
      w12s[q] = s;
    }
    __syncthreads();
    for (int q = t; q < DIM; q += 256) {
      float s = 0.f;
      for (int d = 0; d < DIM; ++d) s = fmaf(Wv[(size_t)d * DIM + q], w12s[d], s);
      wv2[q] = s;
    }
    red[t] = bv[t] * w12s[t] + bv[t + 256] * w12s[t + 256];
    __syncthreads();
    for (int o = 128; o > 0; o >>= 1) {
      if (t < o) red[t] += red[t + o];
      __syncthreads();
    }
    if (t == 0) {
      consts[0] = red[0];  // const1 = bv . w12
      float s = b2[0];
      for (int j = 0; j < HID; ++j) s = fmaf(W2[j], b1[j], s);
      consts[1] = s;       // c0 = W2 . b1 + b2
    }
    return;
  }
  if (bid == 65) {  // u = Wk^T bq
    for (int q = t; q < DIM; q += 256) {
      float s = 0.f;
      for (int d = 0; d < DIM; ++d) s = fmaf(bq[d], Wk[(size_t)d * DIM + q], s);
      u[q] = s;
    }
    return;
  }
  // gmat: Gt[q2][q1] = sum_d Wq[d][q1] Wk[d][q2]
  int tm = t & 15, tn = t >> 4;
  int q1b = (bid & 7) * 64, q2b = (bid >> 3) * 64;
  int lk = t >> 4, lc = (t & 15) * 4;
  float acc[4][4] = {};
  for (int kb = 0; kb < DIM; kb += 16) {
    *(float4*)&As[lk][lc] = *(const float4*)&Wq[(size_t)(kb + lk) * DIM + q1b + lc];
    *(float4*)&Bs[lk][lc] = *(const float4*)&Wk[(size_t)(kb + lk) * DIM + q2b + lc];
    __syncthreads();
#pragma unroll
    for (int k = 0; k < 16; ++k) {
      float4 av = *(float4*)&As[k][tm * 4];
      float4 bv4 = *(float4*)&Bs[k][tn * 4];
      float a[4] = {av.x, av.y, av.z, av.w};
      float b[4] = {bv4.x, bv4.y, bv4.z, bv4.w};
#pragma unroll
      for (int i = 0; i < 4; ++i)
#pragma unroll
        for (int j = 0; j < 4; ++j) acc[i][j] = fmaf(a[i], b[j], acc[i][j]);
    }
    __syncthreads();
  }
#pragma unroll
  for (int i = 0; i < 4; ++i)
#pragma unroll
    for (int j = 0; j < 4; ++j)
      Gt[(size_t)(q2b + tn * 4 + j) * DIM + (q1b + tm * 4 + i)] = f2bf(acc[i][j]);
}

// ---------------- k_vw: vw[n] = Rb16[n] . wv2 + const1 (one wave per row) ----------------
__global__ __launch_bounds__(256) void k_vw(const unsigned short* __restrict__ Rb16,
                                            const float* __restrict__ wv2,
                                            const float* __restrict__ consts,
                                            float* __restrict__ vw) {
  __shared__ float wv2s[512];
  int t = threadIdx.x;
  wv2s[t] = wv2[t];
  wv2s[t + 256] = wv2[t + 256];
  __syncthreads();
  int n = blockIdx.x * 4 + (t >> 6);
  int lane = t & 63;
  bf16x8 rv = *(const bf16x8*)&Rb16[(size_t)n * DIM + lane * 8];
  float s = 0.f;
#pragma unroll
  for (int e = 0; e < 8; ++e) s = fmaf(bf2f((unsigned short)rv[e]), wv2s[lane * 8 + e], s);
#pragma unroll
  for (int o = 32; o > 0; o >>= 1) s += __shfl_xor(s, o);
  if (lane == 0) vw[n] = s + consts[0];
}

// ---------------- k_projT: T = Rb16 @ Gt^T + u, bf16 out (256x256 core) ----------------
__global__ __launch_bounds__(512, 2) void k_projT(const unsigned short* __restrict__ Rb16,
                                                  const unsigned short* __restrict__ Gt,
                                                  const float* __restrict__ u,
                                                  unsigned short* __restrict__ Tb16) {
  __shared__ __align__(16) char smem[131072];
  __shared__ float u_lds[256];
  int t = threadIdx.x;
  size_t rowb = (size_t)blockIdx.x * 256;
  int colb = blockIdx.y * 256;
  if (t < 256) u_lds[t] = u[colb + t];
  f32x4 acc[8][4] = {};
  gemm256_core(Rb16 + rowb * DIM, Gt + (size_t)colb * DIM, smem, acc);
  int lane = t & 63, w = t >> 6, wr = w >> 2, wc = w & 3;
  int lr = lane & 15, kq = lane >> 4;
#pragma unroll
  for (int i = 0; i < 8; ++i)
#pragma unroll
    for (int j = 0; j < 4; ++j)
#pragma unroll
      for (int r = 0; r < 4; ++r) {
        int row = wr * 128 + i * 16 + kq * 4 + r;
        int col = wc * 64 + j * 16 + lr;
        Tb16[(rowb + row) * DIM + colb + col] = f2bf(acc[i][j][r] + u_lds[col]);
      }
}

// ---------------- k_qk: S = T @ R^T (256x256 core) + exp + fused s1/den partials ----------
__global__ __launch_bounds__(512, 2) void k_qk(const unsigned short* __restrict__ Tb16,
                                               const unsigned short* __restrict__ Rb16,
                                               const float* __restrict__ vw,
                                               float* __restrict__ part_s1,
                                               float* __restrict__ part_den) {
  __shared__ __align__(16) char smem[131072];
  __shared__ float vw_lds[256];
  __shared__ float red_s1[4][256], red_den[4][256];
  int t = threadIdx.x;
  // XCD swizzle: each XCD owns one batch (T+R panels fit its 4MB L2)
  int orig = blockIdx.x;
  int wgid = (orig & 7) * 64 + (orig >> 3);
  int b = wgid >> 6;
  int nb = ((wgid >> 3) & 7) * 256;
  int mb = (wgid & 7) * 256;
  if (t < 256) vw_lds[t] = vw[b * SEQ + mb + t];
  f32x4 acc[8][4] = {};
  gemm256_core(Tb16 + ((size_t)b * SEQ + nb) * DIM,
               Rb16 + ((size_t)b * SEQ + mb) * DIM, smem, acc);
  int lane = t & 63, w = t >> 6, wr = w >> 2, wc = w & 3;
  int lr = lane & 15, kq = lane >> 4;
  const float rs = 0.044194173824159216f;  // 1/sqrt(512)
  float vwl[4];
#pragma unroll
  for (int j = 0; j < 4; ++j) vwl[j] = vw_lds[wc * 64 + j * 16 + lr];
#pragma unroll
  for (int i = 0; i < 8; ++i) {
#pragma unroll
    for (int r = 0; r < 4; ++r) {
      float sa = 0.f, sd = 0.f;
#pragma unroll
      for (int j = 0; j < 4; ++j) {
        float e = __expf(acc[i][j][r] * rs);
        sa = fmaf(e, vwl[j], sa);
        sd += e;
      }
#pragma unroll
      for (int m = 1; m < 16; m <<= 1) { sa += __shfl_xor(sa, m); sd += __shfl_xor(sd, m); }
      if (lr == 0) {
        int rl = wr * 128 + i * 16 + kq * 4 + r;
        red_s1[wc][rl] = sa;
        red_den[wc][rl] = sd;
      }
    }
  }
  __syncthreads();
  if (t < 256) {
    size_t o = ((size_t)b * 8 + (mb >> 8)) * SEQ + nb + t;
    part_s1[o] = red_s1[0][t] + red_s1[1][t] + red_s1[2][t] + red_s1[3][t];
    part_den[o] = red_den[0][t] + red_den[1][t] + red_den[2][t] + red_den[3][t];
  }
}

// ---------------- k_final: winner = s1/den + c0 ----------------
__global__ void k_final(const float* __restrict__ part_s1, const float* __restrict__ part_den,
                        const float* __restrict__ consts, float* __restrict__ out) {
  int n = blockIdx.x * 256 + threadIdx.x;
  int b = n >> 11, nn = n & 2047;
  float s1 = 0.f, dn = 0.f;
#pragma unroll
  for (int i = 0; i < 8; ++i) {
    size_t o = ((size_t)b * 8 + i) * SEQ + nn;
    s1 += part_s1[o];
    dn += part_den[o];
  }
  out[n] = s1 / dn + consts[1];
}

extern "C" void kernel_launch(void* const* d_in, const int* in_sizes, int n_in,
                              void* d_out, int out_size, void* d_ws, size_t ws_size,
                              hipStream_t stream) {
  const float* R  = (const float*)d_in[0];
  const float* Wq = (const float*)d_in[1];
  const float* bq = (const float*)d_in[2];
  const float* Wk = (const float*)d_in[3];
  const float* bk = (const float*)d_in[4];  // cancels in row-softmax (kept for signature)
  const float* Wv = (const float*)d_in[5];
  const float* bv = (const float*)d_in[6];
  const float* W1 = (const float*)d_in[7];
  const float* b1 = (const float*)d_in[8];
  const float* W2 = (const float*)d_in[9];
  const float* b2 = (const float*)d_in[10];
  (void)bk;
  float* out = (float*)d_out;

  char* p = (char*)d_ws;
  unsigned short* Rb16 = (unsigned short*)p; p += (size_t)MTOT * DIM * 2;
  unsigned short* Tb16 = (unsigned short*)p; p += (size_t)MTOT * DIM * 2;
  unsigned short* Gt   = (unsigned short*)p; p += (size_t)DIM * DIM * 2;
  float* part_s1  = (float*)p; p += (size_t)BATCH * 8 * SEQ * 4;
  float* part_den = (float*)p; p += (size_t)BATCH * 8 * SEQ * 4;
  float* u      = (float*)p; p += DIM * 4;
  float* wv2    = (float*)p; p += DIM * 4;
  float* vw     = (float*)p; p += MTOT * 4;
  float* consts = (float*)p; p += 16;

  hipLaunchKernelGGL(k_setup, dim3(66 + MTOT * DIM / (256 * 8)), dim3(256), 0, stream,
                     R, Wq, Wk, Wv, bq, bv, W1, b1, W2, b2, Gt, Rb16, u, wv2, consts);
  hipLaunchKernelGGL(k_vw, dim3(MTOT / 4), dim3(256), 0, stream, Rb16, wv2, consts, vw);
  hipLaunchKernelGGL(k_projT, dim3(MTOT / 256, DIM / 256), dim3(512), 0, stream,
                     Rb16, Gt, u, Tb16);
  hipLaunchKernelGGL(k_qk, dim3(512), dim3(512), 0, stream, Tb16, Rb16, vw, part_s1, part_den);
  hipLaunchKernelGGL(k_final, dim3(MTOT / 256), dim3(256), 0, stream,
                     part_s1, part_den, consts, out);
}

// Round 5
// 101.238 us; speedup vs baseline: 17.0479x; 1.1268x over previous
//
#include <hip/hip_runtime.h>
#include <math.h>

#define BATCH 8
#define SEQ 2048
#define DIM 512
#define MTOT (BATCH*SEQ)
#define HID 30

typedef short bf16x8 __attribute__((ext_vector_type(8)));
typedef float f32x4 __attribute__((ext_vector_type(4)));

__device__ __forceinline__ unsigned short f2bf(float f) {
  unsigned int u = __float_as_uint(f);
  unsigned int r = (u + 0x7FFFu + ((u >> 16) & 1u)) >> 16;  // RNE
  return (unsigned short)r;
}

__device__ __forceinline__ void gload_lds16(const void* g, void* l) {
  __builtin_amdgcn_global_load_lds((const __attribute__((address_space(1))) void*)g,
                                   (__attribute__((address_space(3))) void*)l, 16, 0, 0);
}

// ---- 256x256 tile GEMM core: C = A * B^T, A/B row-major [256 rows][K=512] bf16.
// BK=32, 8 waves (2 row x 4 col), 4 LDS buffers (prefetch distance 3, vmcnt(8)).
// Unified macro-row layout: row r = [A chunks s0..3 | B chunks s4..7], 128 B stride,
// physical slot = s ^ (r&7)  (verified zero-conflict geometry).
__device__ __forceinline__ void gemm256_core(const unsigned short* __restrict__ gA,
                                             const unsigned short* __restrict__ gB,
                                             char* smem, f32x4 (&acc)[8][4]) {
  const int t = threadIdx.x;
  const int lane = t & 63;
  const int w = t >> 6;
  const int wr = w >> 2, wc = w & 3;
  const int lr = lane & 15, kc = lane >> 4;
  const int srow = t >> 3;                       // staging row base (0..63)
  const int ss = (t & 7) ^ (srow & 7);           // original slot for this dest chunk
  const unsigned short* gsrc = (ss < 4 ? gA : gB) + (size_t)srow * DIM + (ss & 3) * 8;
  const uint32_t dbase = (uint32_t)(t & 448) * 16;

  auto stage = [&](int buf, int kt) {
#pragma unroll
    for (int q = 0; q < 4; ++q)
      gload_lds16(gsrc + (size_t)(q * 64) * DIM + kt * 32,
                  smem + buf * 32768 + q * 8192 + dbase);
  };

  stage(0, 0); stage(1, 1); stage(2, 2);
  asm volatile("s_waitcnt vmcnt(8)" ::: "memory");
  __builtin_amdgcn_s_barrier();
  asm volatile("" ::: "memory");

#pragma unroll
  for (int kt = 0; kt < 16; ++kt) {
    stage((kt + 3) & 3, (kt + 3 < 16) ? (kt + 3) : 15);  // dummy tail keeps vmcnt uniform
    const char* Ab = smem + (kt & 3) * 32768;
    bf16x8 bfr[4], af[4];
#pragma unroll
    for (int j = 0; j < 4; ++j) {
      int r = wc * 64 + j * 16 + lr;
      bfr[j] = *(const bf16x8*)(Ab + r * 128 + (((4 + kc) ^ (r & 7)) << 4));
    }
#pragma unroll
    for (int i = 0; i < 4; ++i) {
      int r = wr * 128 + i * 16 + lr;
      af[i] = *(const bf16x8*)(Ab + r * 128 + ((kc ^ (r & 7)) << 4));
    }
    __builtin_amdgcn_s_setprio(1);
#pragma unroll
    for (int i = 0; i < 4; ++i)
#pragma unroll
      for (int j = 0; j < 4; ++j)
        acc[i][j] = __builtin_amdgcn_mfma_f32_16x16x32_bf16(af[i], bfr[j], acc[i][j], 0, 0, 0);
    __builtin_amdgcn_s_setprio(0);
#pragma unroll
    for (int i = 0; i < 4; ++i) {
      int r = wr * 128 + (i + 4) * 16 + lr;
      af[i] = *(const bf16x8*)(Ab + r * 128 + ((kc ^ (r & 7)) << 4));
    }
    __builtin_amdgcn_s_setprio(1);
#pragma unroll
    for (int i = 0; i < 4; ++i)
#pragma unroll
      for (int j = 0; j < 4; ++j)
        acc[i + 4][j] = __builtin_amdgcn_mfma_f32_16x16x32_bf16(af[i], bfr[j], acc[i + 4][j], 0, 0, 0);
    __builtin_amdgcn_s_setprio(0);
    asm volatile("s_waitcnt vmcnt(8)" ::: "memory");
    __builtin_amdgcn_s_barrier();
    asm volatile("" ::: "memory");
  }
}

// ---------------- k_weights: 0-63 gmat | 64-95 u | 96-127 wv2 | 128 consts ----------------
__global__ __launch_bounds__(256) void k_weights(
    const float* __restrict__ Wq, const float* __restrict__ Wk, const float* __restrict__ Wv,
    const float* __restrict__ bq, const float* __restrict__ bv,
    const float* __restrict__ W1, const float* __restrict__ b1,
    const float* __restrict__ W2, const float* __restrict__ b2,
    unsigned short* __restrict__ Gt, float* __restrict__ u,
    float* __restrict__ wv2, float* __restrict__ consts) {
  __shared__ __align__(16) float As[16][68];
  __shared__ __align__(16) float Bs[16][68];
  __shared__ float vecs[512];
  __shared__ float red2[16][17];
  const int bid = blockIdx.x;
  const int t = threadIdx.x;

  if (bid < 64) {
    // Gt[q2][q1] = sum_d Wq[d][q1] Wk[d][q2], fp32 accumulate, register-prefetched staging
    int tm = t & 15, tn = t >> 4;
    int q1b = (bid & 7) * 64, q2b = (bid >> 3) * 64;
    int lk = t >> 4, lc = (t & 15) * 4;
    float acc[4][4] = {};
    float4 ra = *(const float4*)&Wq[(size_t)lk * DIM + q1b + lc];
    float4 rb = *(const float4*)&Wk[(size_t)lk * DIM + q2b + lc];
    for (int kb = 0; kb < DIM; kb += 16) {
      *(float4*)&As[lk][lc] = ra;
      *(float4*)&Bs[lk][lc] = rb;
      __syncthreads();
      if (kb + 16 < DIM) {
        ra = *(const float4*)&Wq[(size_t)(kb + 16 + lk) * DIM + q1b + lc];
        rb = *(const float4*)&Wk[(size_t)(kb + 16 + lk) * DIM + q2b + lc];
      }
#pragma unroll
      for (int k = 0; k < 16; ++k) {
        float4 av = *(float4*)&As[k][tm * 4];
        float4 bv4 = *(float4*)&Bs[k][tn * 4];
        float a[4] = {av.x, av.y, av.z, av.w};
        float b[4] = {bv4.x, bv4.y, bv4.z, bv4.w};
#pragma unroll
        for (int i = 0; i < 4; ++i)
#pragma unroll
          for (int j = 0; j < 4; ++j) acc[i][j] = fmaf(a[i], b[j], acc[i][j]);
      }
      __syncthreads();
    }
#pragma unroll
    for (int i = 0; i < 4; ++i)
#pragma unroll
      for (int j = 0; j < 4; ++j)
        Gt[(size_t)(q2b + tn * 4 + j) * DIM + (q1b + tm * 4 + i)] = f2bf(acc[i][j]);
    return;
  }

  if (bid < 128) {
    // k-parallel matvec: u[q] = sum_d bq[d] Wk[d][q]  (bid 64-95)
    //                    wv2[q] = sum_d w12[d] Wv[d][q] (bid 96-127), w12 = W1^T W2
    bool isU = bid < 96;
    int qb = (bid - (isU ? 64 : 96)) * 16;
    if (isU) {
      vecs[t] = bq[t];
      vecs[t + 256] = bq[t + 256];
    } else {
      for (int d = t; d < DIM; d += 256) {
        float s = 0.f;
        for (int j = 0; j < HID; ++j) s = fmaf(W2[j], W1[(size_t)j * DIM + d], s);
        vecs[d] = s;
      }
    }
    __syncthreads();
    const float* M = isU ? Wk : Wv;
    int ql = t & 15, ds = t >> 4;
    float s = 0.f;
#pragma unroll 8
    for (int i = 0; i < 32; ++i) {
      int d = ds * 32 + i;
      s = fmaf(vecs[d], M[(size_t)d * DIM + qb + ql], s);
    }
    red2[ds][ql] = s;
    __syncthreads();
    if (t < 16) {
      float r = 0.f;
#pragma unroll
      for (int k = 0; k < 16; ++k) r += red2[k][t];
      (isU ? u : wv2)[qb + t] = r;
    }
    return;
  }

  // bid == 128: const1 = bv . w12 ; c0 = W2 . b1 + b2
  {
    for (int d = t; d < DIM; d += 256) {
      float s = 0.f;
      for (int j = 0; j < HID; ++j) s = fmaf(W2[j], W1[(size_t)j * DIM + d], s);
      vecs[d] = s;
    }
    __syncthreads();
    float* red = (float*)red2;
    red[t] = bv[t] * vecs[t] + bv[t + 256] * vecs[t + 256];
    __syncthreads();
    for (int o = 128; o > 0; o >>= 1) {
      if (t < o) red[t] += red[t + o];
      __syncthreads();
    }
    if (t == 0) {
      consts[0] = red[0];
      float s = b2[0];
      for (int j = 0; j < HID; ++j) s = fmaf(W2[j], b1[j], s);
      consts[1] = s;
    }
  }
}

// ---------------- k_conv: Rb16 = bf16(R), vw[n] = R[n].wv2 + const1 ----------------
__global__ __launch_bounds__(256) void k_conv(const float* __restrict__ R,
                                              const float* __restrict__ wv2,
                                              const float* __restrict__ consts,
                                              unsigned short* __restrict__ Rb16,
                                              float* __restrict__ vw) {
  int wave = threadIdx.x >> 6, lane = threadIdx.x & 63;
  size_t n = (size_t)blockIdx.x * 4 + wave;
  const float* p = &R[n * DIM + lane * 8];
  float4 r0 = *(const float4*)p;
  float4 r1 = *(const float4*)(p + 4);
  ushort4 lo, hi;
  lo.x = f2bf(r0.x); lo.y = f2bf(r0.y); lo.z = f2bf(r0.z); lo.w = f2bf(r0.w);
  hi.x = f2bf(r1.x); hi.y = f2bf(r1.y); hi.z = f2bf(r1.z); hi.w = f2bf(r1.w);
  *(ushort4*)&Rb16[n * DIM + lane * 8] = lo;
  *(ushort4*)&Rb16[n * DIM + lane * 8 + 4] = hi;
  float4 v0 = *(const float4*)&wv2[lane * 8];
  float4 v1 = *(const float4*)&wv2[lane * 8 + 4];
  float sv = r0.x * v0.x + r0.y * v0.y + r0.z * v0.z + r0.w * v0.w +
             r1.x * v1.x + r1.y * v1.y + r1.z * v1.z + r1.w * v1.w;
#pragma unroll
  for (int o = 32; o > 0; o >>= 1) sv += __shfl_xor(sv, o);
  if (lane == 0) vw[n] = sv + consts[0];
}

// ---------------- k_projT: T = Rb16 @ Gt^T + u, bf16 out (256x256 core) ----------------
__global__ __launch_bounds__(512, 2) void k_projT(const unsigned short* __restrict__ Rb16,
                                                  const unsigned short* __restrict__ Gt,
                                                  const float* __restrict__ u,
                                                  unsigned short* __restrict__ Tb16) {
  __shared__ __align__(16) char smem[131072];
  __shared__ float u_lds[256];
  int t = threadIdx.x;
  size_t rowb = (size_t)blockIdx.x * 256;
  int colb = blockIdx.y * 256;
  if (t < 256) u_lds[t] = u[colb + t];
  f32x4 acc[8][4] = {};
  gemm256_core(Rb16 + rowb * DIM, Gt + (size_t)colb * DIM, smem, acc);
  int lane = t & 63, w = t >> 6, wr = w >> 2, wc = w & 3;
  int lr = lane & 15, kq = lane >> 4;
#pragma unroll
  for (int i = 0; i < 8; ++i)
#pragma unroll
    for (int j = 0; j < 4; ++j)
#pragma unroll
      for (int r = 0; r < 4; ++r) {
        int row = wr * 128 + i * 16 + kq * 4 + r;
        int col = wc * 64 + j * 16 + lr;
        Tb16[(rowb + row) * DIM + colb + col] = f2bf(acc[i][j][r] + u_lds[col]);
      }
}

// ---------------- k_qk: S = T @ R^T (256x256 core) + exp + fused s1/den partials ----------
__global__ __launch_bounds__(512, 2) void k_qk(const unsigned short* __restrict__ Tb16,
                                               const unsigned short* __restrict__ Rb16,
                                               const float* __restrict__ vw,
                                               float* __restrict__ part_s1,
                                               float* __restrict__ part_den) {
  __shared__ __align__(16) char smem[131072];
  __shared__ float vw_lds[256];
  __shared__ float red_s1[4][256], red_den[4][256];
  int t = threadIdx.x;
  // XCD swizzle: each XCD owns one batch (T+R panels fit its 4MB L2)
  int orig = blockIdx.x;
  int wgid = (orig & 7) * 64 + (orig >> 3);
  int b = wgid >> 6;
  int nb = ((wgid >> 3) & 7) * 256;
  int mb = (wgid & 7) * 256;
  if (t < 256) vw_lds[t] = vw[b * SEQ + mb + t];
  f32x4 acc[8][4] = {};
  gemm256_core(Tb16 + ((size_t)b * SEQ + nb) * DIM,
               Rb16 + ((size_t)b * SEQ + mb) * DIM, smem, acc);
  int lane = t & 63, w = t >> 6, wr = w >> 2, wc = w & 3;
  int lr = lane & 15, kq = lane >> 4;
  const float rs = 0.044194173824159216f;  // 1/sqrt(512)
  float vwl[4];
#pragma unroll
  for (int j = 0; j < 4; ++j) vwl[j] = vw_lds[wc * 64 + j * 16 + lr];
#pragma unroll
  for (int i = 0; i < 8; ++i) {
#pragma unroll
    for (int r = 0; r < 4; ++r) {
      float sa = 0.f, sd = 0.f;
#pragma unroll
      for (int j = 0; j < 4; ++j) {
        float e = __expf(acc[i][j][r] * rs);
        sa = fmaf(e, vwl[j], sa);
        sd += e;
      }
#pragma unroll
      for (int m = 1; m < 16; m <<= 1) { sa += __shfl_xor(sa, m); sd += __shfl_xor(sd, m); }
      if (lr == 0) {
        int rl = wr * 128 + i * 16 + kq * 4 + r;
        red_s1[wc][rl] = sa;
        red_den[wc][rl] = sd;
      }
    }
  }
  __syncthreads();
  if (t < 256) {
    size_t o = ((size_t)b * 8 + (mb >> 8)) * SEQ + nb + t;
    part_s1[o] = red_s1[0][t] + red_s1[1][t] + red_s1[2][t] + red_s1[3][t];
    part_den[o] = red_den[0][t] + red_den[1][t] + red_den[2][t] + red_den[3][t];
  }
}

// ---------------- k_final: winner = s1/den + c0 ----------------
__global__ void k_final(const float* __restrict__ part_s1, const float* __restrict__ part_den,
                        const float* __restrict__ consts, float* __restrict__ out) {
  int n = blockIdx.x * 256 + threadIdx.x;
  int b = n >> 11, nn = n & 2047;
  float s1 = 0.f, dn = 0.f;
#pragma unroll
  for (int i = 0; i < 8; ++i) {
    size_t o = ((size_t)b * 8 + i) * SEQ + nn;
    s1 += part_s1[o];
    dn += part_den[o];
  }
  out[n] = s1 / dn + consts[1];
}

extern "C" void kernel_launch(void* const* d_in, const int* in_sizes, int n_in,
                              void* d_out, int out_size, void* d_ws, size_t ws_size,
                              hipStream_t stream) {
  const float* R  = (const float*)d_in[0];
  const float* Wq = (const float*)d_in[1];
  const float* bq = (const float*)d_in[2];
  const float* Wk = (const float*)d_in[3];
  const float* bk = (const float*)d_in[4];  // cancels in row-softmax
  const float* Wv = (const float*)d_in[5];
  const float* bv = (const float*)d_in[6];
  const float* W1 = (const float*)d_in[7];
  const float* b1 = (const float*)d_in[8];
  const float* W2 = (const float*)d_in[9];
  const float* b2 = (const float*)d_in[10];
  (void)bk;
  float* out = (float*)d_out;

  char* p = (char*)d_ws;
  unsigned short* Rb16 = (unsigned short*)p; p += (size_t)MTOT * DIM * 2;
  unsigned short* Tb16 = (unsigned short*)p; p += (size_t)MTOT * DIM * 2;
  unsigned short* Gt   = (unsigned short*)p; p += (size_t)DIM * DIM * 2;
  float* part_s1  = (float*)p; p += (size_t)BATCH * 8 * SEQ * 4;
  float* part_den = (float*)p; p += (size_t)BATCH * 8 * SEQ * 4;
  float* u      = (float*)p; p += DIM * 4;
  float* wv2    = (float*)p; p += DIM * 4;
  float* vw     = (float*)p; p += MTOT * 4;
  float* consts = (float*)p; p += 16;

  hipLaunchKernelGGL(k_weights, dim3(129), dim3(256), 0, stream,
                     Wq, Wk, Wv, bq, bv, W1, b1, W2, b2, Gt, u, wv2, consts);
  hipLaunchKernelGGL(k_conv, dim3(MTOT / 4), dim3(256), 0, stream, R, wv2, consts, Rb16, vw);
  hipLaunchKernelGGL(k_projT, dim3(MTOT / 256, DIM / 256), dim3(512), 0, stream,
                     Rb16, Gt, u, Tb16);
  hipLaunchKernelGGL(k_qk, dim3(512), dim3(512), 0, stream, Tb16, Rb16, vw, part_s1, part_den);
  hipLaunchKernelGGL(k_final, dim3(MTOT / 256), dim3(256), 0, stream,
                     part_s1, part_den, consts, out);
}